// Round 16
// baseline (297.230 us; speedup 1.0000x reference)
//
#include <hip/hip_runtime.h>
#include <stdint.h>

#define BB 128
#define TT 3000
#define CC 64
#define LL 128
// S = 2L+1 = 257 ; states 0..255 on 2 consumer waves; state 256 via tail pass
#define NEGf (-1e30f)
#define LOG2E 1.4426950408889634f
#define LN2f 0.6931471805599453f
#define F 12                  // frames per ring chunk; 3000 = 250 * 12
#define NCH 250
#define NULLM (-30000)        // null exponent, far below any live m
#define LSE_BLOCKS 512

typedef float f32x2 __attribute__((ext_vector_type(2)));
typedef float f32x4 __attribute__((ext_vector_type(4)));

__device__ __forceinline__ float fexp2(float x){ return __builtin_amdgcn_exp2f(x); }
__device__ __forceinline__ float flog2(float x){ return __builtin_amdgcn_logf(x); }
__device__ __forceinline__ int dpp_shr1_i(int x, int old){
    return __builtin_amdgcn_update_dpp(old, x, 0x138, 0xF, 0xF, false);
}
__device__ __forceinline__ float dpp_shr1_f(float x, float old){
    int r = __builtin_amdgcn_update_dpp(__float_as_int(old), __float_as_int(x),
                                        0x138, 0xF, 0xF, false);
    return __int_as_float(r);
}
#define DPPMAXT(x,c) fmaxf((x),__int_as_float(__builtin_amdgcn_update_dpp(0,__float_as_int(x),(c),0xF,0xF,true)))
#define DPPADDT(x,c) ((x)+__int_as_float(__builtin_amdgcn_update_dpp(0,__float_as_int(x),(c),0xF,0xF,true)))
#define RED64(OP,x) { x=OP(x,0x111); x=OP(x,0x112); x=OP(x,0x114); x=OP(x,0x118); x=OP(x,0x142); x=OP(x,0x143); }
#define MWALL() asm volatile("" ::: "memory")

// Fused kernel, 512 threads/block, NO per-chunk barriers in scan blocks.
// waves 0,1 = consumers: lane l of wave W owns states 128W+2l (a0) and
// 128W+2l+1 (a1) as (m:int, r:f32 in [0.5,1)), value 2^m*r. Steps are exact
// linear arithmetic (ldexp/add/frexp-by-bits), zero transcendentals on chain.
// waves 2-7 = producers: free-run up to 4 chunks ahead staging em=2^(x*log2e)
// (plain f32) into a 4-slot ring; flag sync: cnt[slot] monotonic (+6/cycle),
// prog_a (wave0 done), prog_c1 (wave1 done, gates slot reuse).
__global__ __launch_bounds__(512) void fused_kernel(const float* __restrict__ in,
                                                    const int* __restrict__ tgt,
                                                    float* __restrict__ lse,
                                                    float* __restrict__ ll2){
    __shared__ __align__(16) float emR[4][F][132];  // [slot][frame][0..127 em_tgt,128 em_blank]
    __shared__ __align__(16) float bndR[5][F][2];   // (m,r) of state 127 per step
    __shared__ __align__(16) f32x2 laP[3008];       // (m,r) of state 255 per t
    __shared__ float lbL[3008];                     // log2 em_blank per t
    __shared__ int flg[8];                          // [0..3]=cnt, [4]=prog_a, [5]=prog_c1
    if (blockIdx.x < BB) {
        const int b = blockIdx.x;
        const int wave = threadIdx.x >> 6;
        const int lane = threadIdx.x & 63;
        const float* fb = in + (size_t)b * TT * CC;
        const uint32_t em_base  = (uint32_t)(uintptr_t)&emR[0][0][0];
        const uint32_t bnd_base = (uint32_t)(uintptr_t)&bndR[0][0][0];
        volatile int* cntp = (volatile int*)&flg[0];
        volatile int* pap  = (volatile int*)&flg[4];
        volatile int* pc1p = (volatile int*)&flg[5];
        if (threadIdx.x == 0) {
            #pragma unroll
            for (int k = 0; k < 8; ++k) flg[k] = 0;
        }
        if (threadIdx.x < 8) {
            laP[3000 + threadIdx.x] = (f32x2){__int_as_float(NULLM), 0.5f};
            lbL[3000 + threadIdx.x] = 0.f;
        }
        __syncthreads();   // single startup barrier

        if (wave < 2) {
            // ---------------- consumers ----------------
            const int W = wave;
            __builtin_amdgcn_s_setprio(1);
            int a0m = NULLM, a1m = NULLM; float a0r = 0.5f, a1r = 0.5f;
            if (W == 0 && lane == 0) a0m = 1;        // alpha=1.0 virtual pre-state
            int plm = NULLM; float plr = 0.5f;       // wave0: alpha127(t-1) carry
            for (int x = 0; x < NCH; ++x) {
                const int slot4 = x & 3;
                const int slot5 = x % 5;
                if (W == 0) {
                    const int need = 6 * ((x >> 2) + 1);
                    int v = cntp[slot4];
                    while (v < need) { __builtin_amdgcn_s_sleep(1); v = cntp[slot4]; }
                } else {
                    int v = *pap;
                    while (v < x + 1) { __builtin_amdgcn_s_sleep(1); v = *pap; }
                }
                const uint32_t ra = em_base + (uint32_t)slot4*6336u + (64u*W + (uint32_t)lane)*4u;
                const uint32_t rb = em_base + (uint32_t)slot4*6336u + 512u;
                f32x4 B4[6];
                if (W == 1) {
                    const uint32_t rq = bnd_base + (uint32_t)slot5*96u;
                    asm volatile("ds_read_b128 %0, %1 offset:0"  : "=v"(B4[0]) : "v"(rq));
                    asm volatile("ds_read_b128 %0, %1 offset:16" : "=v"(B4[1]) : "v"(rq));
                    asm volatile("ds_read_b128 %0, %1 offset:32" : "=v"(B4[2]) : "v"(rq));
                    asm volatile("ds_read_b128 %0, %1 offset:48" : "=v"(B4[3]) : "v"(rq));
                    asm volatile("ds_read_b128 %0, %1 offset:64" : "=v"(B4[4]) : "v"(rq));
                    asm volatile("ds_read_b128 %0, %1 offset:80" : "=v"(B4[5]) : "v"(rq));
                } else {
                    #pragma unroll
                    for (int k = 0; k < 6; ++k)
                        B4[k] = (f32x4){__int_as_float(NULLM), 0.5f, __int_as_float(NULLM), 0.5f};
                }
                float E[F], Bv[F]; int hm[F]; float hr[F];
                asm volatile("ds_read_b32 %0, %1 offset:0"    : "=v"(E[0])  : "v"(ra));
                asm volatile("ds_read_b32 %0, %1 offset:0"    : "=v"(Bv[0]) : "v"(rb));
                asm volatile("ds_read_b32 %0, %1 offset:528"  : "=v"(E[1])  : "v"(ra));
                asm volatile("ds_read_b32 %0, %1 offset:528"  : "=v"(Bv[1]) : "v"(rb));
                asm volatile("ds_read_b32 %0, %1 offset:1056" : "=v"(E[2])  : "v"(ra));
                asm volatile("ds_read_b32 %0, %1 offset:1056" : "=v"(Bv[2]) : "v"(rb));
                #pragma unroll
                for (int j = 0; j < F; ++j) {
                    if (j + 3 < F) {
                        asm volatile("ds_read_b32 %0, %1 offset:%2" : "=v"(E[j+3])  : "v"(ra), "n"((j+3)*528));
                        asm volatile("ds_read_b32 %0, %1 offset:%2" : "=v"(Bv[j+3]) : "v"(rb), "n"((j+3)*528));
                        asm volatile("s_waitcnt lgkmcnt(6)" ::: "memory");
                    } else if (j + 3 == F) {
                        asm volatile("s_waitcnt lgkmcnt(4)" ::: "memory");
                    } else if (j + 2 == F) {
                        asm volatile("s_waitcnt lgkmcnt(2)" ::: "memory");
                    } else {
                        asm volatile("s_waitcnt lgkmcnt(0)" ::: "memory");
                    }
                    __builtin_amdgcn_sched_barrier(0);   // rule #18
                    const int   bjm = __float_as_int((j&1) ? B4[j>>1].z : B4[j>>1].x);
                    const float bjr = (j&1) ? B4[j>>1].w : B4[j>>1].y;
                    int   p1m = dpp_shr1_i(a1m, NULLM);
                    float p1r = dpp_shr1_f(a1r, 0.5f);
                    p1m = (lane == 0) ? bjm : p1m;
                    p1r = (lane == 0) ? bjr : p1r;
                    // even: a0' = emB (x) (a0 (+) p1)    [exact extended-range]
                    int Mt = (a0m > p1m) ? a0m : p1m;
                    float rs = ldexpf(a0r, a0m - Mt) + ldexpf(p1r, p1m - Mt);
                    float pr = rs * Bv[j];
                    int ui = __float_as_int(pr);
                    int n0m = Mt + ((ui >> 23) - 126);
                    float n0r = __int_as_float((ui & 0x7FFFFF) | 0x3F000000);
                    // odd: a1' = em1 (x) (a1 (+) a0 (+) p1)
                    int Mu = (Mt > a1m) ? Mt : a1m;
                    float ru = ldexpf(a1r, a1m - Mu) + ldexpf(a0r, a0m - Mu)
                             + ldexpf(p1r, p1m - Mu);
                    float qu = ru * E[j];
                    int uj = __float_as_int(qu);
                    int n1m = Mu + ((uj >> 23) - 126);
                    float n1r = __int_as_float((uj & 0x7FFFFF) | 0x3F000000);
                    a0m = n0m; a0r = n0r; a1m = n1m; a1r = n1r;
                    hm[j] = a1m; hr[j] = a1r;
                }
                if (W == 0) {
                    if (lane == 63) {   // boundary hand-off: [prev_last, hist[0..10]]
                        float* s = &bndR[slot5][0][0];
                        s[0] = __int_as_float(plm); s[1] = plr;
                        #pragma unroll
                        for (int j = 0; j < F-1; ++j) {
                            s[(j+1)*2] = __int_as_float(hm[j]); s[(j+1)*2+1] = hr[j];
                        }
                    }
                    plm = hm[F-1]; plr = hr[F-1];
                    MWALL();
                    *pap = x + 1;
                } else {
                    if (lane == 63) {
                        #pragma unroll
                        for (int j = 0; j < F; ++j)
                            laP[x*F + j] = (f32x2){__int_as_float(hm[j]), hr[j]};
                    }
                    MWALL();
                    *pc1p = x + 1;
                }
            }
        } else {
            // ---------------- producers: wave p stages frames {p, p+6} ----------------
            const int p = wave - 2;
            const int t0 = tgt[b*LL + lane];         // channel for em slot lane
            const int t1 = tgt[b*LL + 64 + lane];    // channel for em slot 64+lane
            float Av0[2], Av1[2], Avb[2], Bw0[2], Bw1[2], Bwb[2];
#define LOADP(S, c) { const float* cb_ = fb + (size_t)(c)*(F*CC); \
            _Pragma("unroll") for (int k = 0; k < 2; ++k) { \
                const float* fr_ = cb_ + (p + 6*k)*CC; \
                S##0[k] = fr_[t0]; S##1[k] = fr_[t1]; S##b[k] = fr_[63]; } }
#define STORP(S, c) { const int buf_ = (c) & 3; \
            _Pragma("unroll") for (int k = 0; k < 2; ++k) { \
                const int f_ = p + 6*k; \
                emR[buf_][f_][lane]    = fexp2(S##0[k]*LOG2E); \
                emR[buf_][f_][64+lane] = fexp2(S##1[k]*LOG2E); \
                if (lane == 0) { float xb_ = S##b[k]*LOG2E; \
                    emR[buf_][f_][128] = fexp2(xb_); lbL[(c)*F + f_] = xb_; } } }
#define PPOLL(c) { const int need_ = (c) - 3; int v_ = *pc1p; \
            while (v_ < need_) { __builtin_amdgcn_s_sleep(2); v_ = *pc1p; } }
            LOADP(Av, 0);
            for (int c = 0; c < NCH; c += 2) {
                if (c + 1 < NCH) LOADP(Bw, c + 1);
                MWALL();
                PPOLL(c); STORP(Av, c); MWALL();
                atomicAdd((int*)&flg[c & 3], 1);
                if (c + 1 < NCH) {
                    if (c + 2 < NCH) LOADP(Av, c + 2);
                    MWALL();
                    PPOLL(c + 1); STORP(Bw, c + 1); MWALL();
                    atomicAdd((int*)&flg[(c + 1) & 3], 1);
                }
            }
        }
        __syncthreads();   // single tail barrier
        if (wave == 0) {
            // la256(T-1) = lse_{tau<=T-2}( la255(tau) + CBtot - CB(tau) )  [R13-verified]
            const int base = lane * 47;              // 3008 = 64*47
            float seg = 0.f;
            for (int k = 0; k < 47; ++k) seg += lbL[base + k];
            float inc = seg;
            #pragma unroll
            for (int d = 1; d < 64; d <<= 1) {
                float t = __shfl_up(inc, d, 64);
                if (lane >= d) inc += t;
            }
            float CBtot = __int_as_float(__builtin_amdgcn_readlane(__float_as_int(inc), 63));
            float ex = inc - seg;
            float cb = ex, gm = NEGf;
            for (int k = 0; k < 47; ++k) {
                int idx = base + k;
                cb += lbL[idx];
                f32x2 lp = laP[idx];
                float g = (float)__float_as_int(lp.x) + flog2(lp.y) + (CBtot - cb);
                g = (idx == 2999) ? NEGf : g;
                gm = fmaxf(gm, g);
            }
            RED64(DPPMAXT, gm);
            float gmax = __int_as_float(__builtin_amdgcn_readlane(__float_as_int(gm), 63));
            cb = ex; float se = 0.f;
            for (int k = 0; k < 47; ++k) {
                int idx = base + k;
                cb += lbL[idx];
                f32x2 lp = laP[idx];
                float g = (float)__float_as_int(lp.x) + flog2(lp.y) + (CBtot - cb);
                g = (idx == 2999) ? NEGf : g;
                se += fexp2(g - gmax);
            }
            RED64(DPPADDT, se);
            float S = __int_as_float(__builtin_amdgcn_readlane(__float_as_int(se), 63));
            float la256 = gmax + flog2(S);
            f32x2 lp9 = laP[2999];
            float la255f = (float)__float_as_int(lp9.x) + flog2(lp9.y);
            float m = fmaxf(la255f, la256);
            float r = m + flog2(1.0f + fexp2(-fabsf(la255f - la256)));
            if (lane == 0) ll2[b] = r;
        }
        return;
    }
    // ---- softmax normalizer: one wave per (b,t) row, grid-strided ----
    int wv = (blockIdx.x - BB) * 8 + (threadIdx.x >> 6);
    int lane = threadIdx.x & 63;
    const int stride = LSE_BLOCKS * 8;
    for (int row = wv; row < BB * TT; row += stride) {
        float x = in[(size_t)row * CC + lane];
        float m = x;
        #pragma unroll
        for (int d = 32; d >= 1; d >>= 1) m = fmaxf(m, __shfl_xor(m, d, 64));
        float s = fexp2((x - m) * LOG2E);
        #pragma unroll
        for (int d = 32; d >= 1; d >>= 1) s += __shfl_xor(s, d, 64);
        if (lane == 0) lse[row] = m + flog2(s) * LN2f;
    }
}

// per-batch loss_b = sum_t lse_nat[b,t] - ll2[b]*ln2
__global__ __launch_bounds__(256) void bsum_kernel(const float* __restrict__ lse,
                                                   const float* __restrict__ ll2,
                                                   float* __restrict__ lossb) {
    __shared__ float red[256];
    int b = blockIdx.x;
    float s = 0.f;
    for (int i = threadIdx.x; i < TT; i += 256) s += lse[(size_t)b * TT + i];
    red[threadIdx.x] = s;
    __syncthreads();
    #pragma unroll
    for (int w = 128; w >= 1; w >>= 1) {
        if (threadIdx.x < w) red[threadIdx.x] += red[threadIdx.x + w];
        __syncthreads();
    }
    if (threadIdx.x == 0) lossb[b] = red[0] - ll2[b] * LN2f;
}

// mean over batch
__global__ __launch_bounds__(64) void final_kernel(const float* __restrict__ lossb,
                                                   float* __restrict__ out) {
    int lane = threadIdx.x;
    float v = lossb[lane] + lossb[lane + 64];
    #pragma unroll
    for (int d = 32; d >= 1; d >>= 1) v += __shfl_xor(v, d, 64);
    if (lane == 0) out[0] = v / (float)BB;
}

extern "C" void kernel_launch(void* const* d_in, const int* in_sizes, int n_in,
                              void* d_out, int out_size, void* d_ws, size_t ws_size,
                              hipStream_t stream) {
    const float* in = (const float*)d_in[0];
    const int* tg = (const int*)d_in[1];
    float* out = (float*)d_out;
    float* lse = (float*)d_ws;                 // B*T floats
    float* ll2 = lse + (size_t)BB * TT;        // B floats
    float* lossb = ll2 + BB;                   // B floats

    hipLaunchKernelGGL(fused_kernel, dim3(BB + LSE_BLOCKS), dim3(512), 0, stream,
                       in, tg, lse, ll2);
    hipLaunchKernelGGL(bsum_kernel, dim3(BB), dim3(256), 0, stream, lse, ll2, lossb);
    hipLaunchKernelGGL(final_kernel, dim3(1), dim3(64), 0, stream, lossb, out);
}

// Round 17
// 262.933 us; speedup vs baseline: 1.1304x; 1.1304x over previous
//
#include <hip/hip_runtime.h>
#include <stdint.h>

#define BB 128
#define TT 3000
#define CC 64
#define LL 128
// S = 2L+1 = 257 ; states 0..127 wave0, 128..255 wave1, 256 wave2
#define LOG2E 1.4426950408889634f
#define LN2f 0.6931471805599453f
#define F 24                  // frames per ring chunk; 3000 = 125 * 24
#define NCH 125
#define NPH (NCH + 2)         // wave1 lags 1 chunk, wave2 lags 2
#define LSE_BLOCKS 512

typedef double f64x2 __attribute__((ext_vector_type(2)));

__device__ __forceinline__ float fexp2(float x){ return __builtin_amdgcn_exp2f(x); }
__device__ __forceinline__ float flog2(float x){ return __builtin_amdgcn_logf(x); }

// lane l <- lane l-1 of x; lanes with no source (lane 0) get `old`. 2 issue slots.
__device__ __forceinline__ double dpp_shr1_f64(double x, double old){
    int rl = __builtin_amdgcn_update_dpp(__double2loint(old), __double2loint(x),
                                         0x138, 0xF, 0xF, false);
    int rh = __builtin_amdgcn_update_dpp(__double2hiint(old), __double2hiint(x),
                                         0x138, 0xF, 0xF, false);
    return __hiloint2double(rh, rl);
}
__device__ __forceinline__ int imax(int a, int b){ return a > b ? a : b; }
#define DPPMAXI(x,c) imax((x), __builtin_amdgcn_update_dpp(0,(x),(c),0xF,0xF,true))
#define RED64I(x) { x=DPPMAXI(x,0x111); x=DPPMAXI(x,0x112); x=DPPMAXI(x,0x114); \
                    x=DPPMAXI(x,0x118); x=DPPMAXI(x,0x142); x=DPPMAXI(x,0x143); }

// Fused kernel, 512 threads/block.
// Scan blocks: wave0 = states 0..127 (2/lane, f64), wave1 = states 128..255
// (lags 1 chunk), wave2 = state 256 (lags 2). Linear-domain f64 recursion:
// per step only {dpp2, add, mul, add, mul, stash-write} on the serial wave —
// attacks the measured ~7.5cy/inst single-wave issue floor. Per-chunk
// wave-uniform power-of-2 renorm, per-wave Eacc, boundary values scale-aligned
// via ldexp(dE). Waves 3..7 = producers (T14 split), staging f64 em.
__global__ __launch_bounds__(512) void fused_kernel(const float* __restrict__ in,
                                                    const int* __restrict__ tgt,
                                                    float* __restrict__ lse,
                                                    float* __restrict__ ll2){
    __shared__ __align__(16) double emE2[3][128][F]; // [buf][state-slot][frame]
    __shared__ __align__(16) double emB4[4][F];      // blank em, mod-4 ring
    __shared__ __align__(16) double st01[2][F];      // alpha(127,t) stash ring
    __shared__ __align__(16) double st12[2][F];      // alpha(255,t) stash ring
    __shared__ double dump[96];
    __shared__ int stTag0[2], stTag1[2];             // Eacc scale tags for stashes
    if (blockIdx.x < BB) {
        const int b = blockIdx.x;
        const int wave = threadIdx.x >> 6;
        const int lane = threadIdx.x & 63;
        const float* fb = in + (size_t)b * TT * CC;
        const uint32_t emE_b = (uint32_t)(uintptr_t)&emE2[0][0][0];
        const uint32_t emB_b = (uint32_t)(uintptr_t)&emB4[0][0];
        const uint32_t st01_b = (uint32_t)(uintptr_t)&st01[0][0];
        const uint32_t st12_b = (uint32_t)(uintptr_t)&st12[0][0];
        const uint32_t dump_b = (uint32_t)(uintptr_t)&dump[0];

        if (wave >= 3) {
            // ---------------- producers: 5 waves, frames p*5+k (k<5, f<24) ----------------
            const int p = wave - 3;
            const int t0 = tgt[b*LL + lane];        // channel for state-slot lane
            const int t1 = tgt[b*LL + 64 + lane];   // channel for state-slot 64+lane
            float v0[5], v1[5], vb[5];
            auto loadc = [&](int cc){
                const float* cbase = fb + (size_t)cc * F * CC;
                #pragma unroll
                for (int k = 0; k < 5; ++k) {
                    int f = p*5 + k;
                    if (f < F) {
                        const float* fr = cbase + f*CC;
                        v0[k] = fr[t0]; v1[k] = fr[t1]; vb[k] = fr[63];
                    }
                }
            };
            auto storec = [&](int cc){
                const int b3 = cc % 3, bm4 = cc & 3;
                #pragma unroll
                for (int k = 0; k < 5; ++k) {
                    int f = p*5 + k;
                    if (f < F) {
                        emE2[b3][lane][f]    = (double)fexp2(v0[k]*LOG2E);
                        emE2[b3][64+lane][f] = (double)fexp2(v1[k]*LOG2E);
                        if (lane == 0) emB4[bm4][f] = (double)fexp2(vb[k]*LOG2E);
                    }
                }
            };
            loadc(0); storec(0); loadc(1);
            __syncthreads();
            for (int ph = 0; ph < NPH; ++ph) {
                if (ph + 1 < NCH) storec(ph + 1);
                if (ph + 2 < NCH) loadc(ph + 2);
                __syncthreads();
            }
            return;
        }
        __syncthreads();   // startup barrier (consumers)

        if (wave < 2) {
            // ------------- consumer waves 0,1: 2 states/lane, f64 linear -------------
            const int W = wave;
            __builtin_amdgcn_s_setprio(1);
            double a0 = (W == 0 && lane == 0) ? 1.0 : 0.0;  // virtual pre-t=0 state
            double a1 = 0.0;
            double carry = 0.0;          // wave1: alpha(127) at last t of prev chunk
            int Eacc = 0, eprev = 0;
            const uint32_t myE = emE_b + (uint32_t)((64*W + lane) * (F*8));
            const uint32_t stW = W ? st12_b : st01_b;    // my outgoing stash
            for (int ph = 0; ph < NPH; ++ph) {
                const int x = ph - W;
                if (x >= 0 && x < NCH) {
                    const int b3 = x % 3, bm4 = x & 3, s2 = x & 1;
                    double ph_[F];
                    int dE = 0;
                    if (W == 1) {                     // boundary scale alignment
                        int ea0 = stTag0[s2];
                        if (eprev == 0) Eacc = ea0;   // dead-adopt upstream scale
                        dE = ea0 - Eacc;
                    }
                    if (lane == 0) { if (W) stTag1[s2] = Eacc; else stTag0[s2] = Eacc; }
                    // ---- batched chunk reads into registers ----
                    f64x2 E2[F/2], B2[F/2], P2[F/2];
                    const uint32_t ra = myE + (uint32_t)b3 * (128*F*8);
                    const uint32_t rb = emB_b + (uint32_t)bm4 * (F*8);
                    const uint32_t rp = st01_b + (uint32_t)s2 * (F*8);
                    #pragma unroll
                    for (int i = 0; i < F/2; ++i)
                        asm volatile("ds_read_b128 %0, %1 offset:%2" : "=v"(E2[i]) : "v"(ra), "n"(i*16));
                    #pragma unroll
                    for (int i = 0; i < F/2; ++i)
                        asm volatile("ds_read_b128 %0, %1 offset:%2" : "=v"(B2[i]) : "v"(rb), "n"(i*16));
                    if (W == 1) {
                        #pragma unroll
                        for (int i = 0; i < F/2; ++i)
                            asm volatile("ds_read_b128 %0, %1 offset:%2" : "=v"(P2[i]) : "v"(rp), "n"(i*16));
                    }
                    asm volatile("s_waitcnt lgkmcnt(0)" ::: "memory");
                    __builtin_amdgcn_sched_barrier(0);   // rule #18
                    if (W == 1) {
                        #pragma unroll
                        for (int j = 0; j < F; ++j) ph_[j] = ldexp(P2[j>>1][j&1], dE);
                    }
                    const uint32_t sta = (lane == 63) ? (stW + (uint32_t)s2*(F*8))
                                                     : (dump_b + (uint32_t)lane*8);
                    // ---- 24 steps, pure-register serial chain ----
                    #pragma unroll
                    for (int j = 0; j < F; ++j) {
                        double inj = (W == 1) ? ((j == 0) ? carry : ph_[j-1]) : 0.0;
                        double p3 = dpp_shr1_f64(a1, inj);    // state 2l-1 (t-1)
                        double t_ = a0 + p3;
                        a0 = B2[j>>1][j&1] * t_;              // even: emB*(a0+p3)
                        double u_ = a1 + t_;
                        a1 = E2[j>>1][j&1] * u_;              // odd: em*(a1+a0+p3)
                        asm volatile("ds_write_b64 %0, %1 offset:%2"
                                     :: "v"(sta), "v"(a1), "n"(j*8));
                    }
                    if (W == 1) carry = ph_[F-1];
                    // ---- per-chunk wave-uniform renorm (power of 2, Eacc tracks) ----
                    int e0 = (__double2hiint(a0) >> 20) & 0x7FF;
                    int e1 = (__double2hiint(a1) >> 20) & 0x7FF;
                    int e = imax(e0, e1);
                    RED64I(e);
                    int eu = __builtin_amdgcn_readlane(e, 63);
                    double f = __hiloint2double((2045 - eu) << 20, 0);  // 2^(1022-eu)
                    if (eu != 0) {
                        a0 *= f; a1 *= f; carry *= f;
                        Eacc += eu - 1022;
                    }
                    eprev = eu;
                }
                __syncthreads();
            }
            return;
        }
        // ------------- wave2: state 256 (lags 2 chunks) + final ll2 -------------
        {
            double a4 = 0.0, carry255 = 0.0;
            int Eacc = 0, eprev = 0;
            for (int ph = 0; ph < NPH; ++ph) {
                const int x = ph - 2;
                if (x >= 0 && x < NCH) {
                    const int bm4 = x & 3, s2 = x & 1;
                    int ea1 = stTag1[s2];
                    if (eprev == 0) Eacc = ea1;
                    int dE = ea1 - Eacc;
                    f64x2 B2[F/2], P2[F/2];
                    const uint32_t rb = emB_b + (uint32_t)bm4 * (F*8);
                    const uint32_t rp = st12_b + (uint32_t)s2 * (F*8);
                    #pragma unroll
                    for (int i = 0; i < F/2; ++i)
                        asm volatile("ds_read_b128 %0, %1 offset:%2" : "=v"(B2[i]) : "v"(rb), "n"(i*16));
                    #pragma unroll
                    for (int i = 0; i < F/2; ++i)
                        asm volatile("ds_read_b128 %0, %1 offset:%2" : "=v"(P2[i]) : "v"(rp), "n"(i*16));
                    asm volatile("s_waitcnt lgkmcnt(0)" ::: "memory");
                    __builtin_amdgcn_sched_barrier(0);
                    double ph_[F];
                    #pragma unroll
                    for (int j = 0; j < F; ++j) ph_[j] = ldexp(P2[j>>1][j&1], dE);
                    #pragma unroll
                    for (int j = 0; j < F; ++j) {
                        double inj = (j == 0) ? carry255 : ph_[j-1];
                        a4 = B2[j>>1][j&1] * (a4 + inj);   // alpha256 = emB*(a256+a255)
                    }
                    carry255 = ph_[F-1];
                    int e0 = (__double2hiint(a4) >> 20) & 0x7FF;
                    int e1 = (__double2hiint(carry255) >> 20) & 0x7FF;
                    int eu = imax(e0, e1);
                    double f = __hiloint2double((2045 - eu) << 20, 0);
                    if (eu != 0) { a4 *= f; carry255 *= f; Eacc += eu - 1022; }
                    eprev = eu;
                }
                __syncthreads();
            }
            if (lane == 0) {   // final: ll2 = log2(alpha255 + alpha256) + Eacc
                double s = a4 + carry255;
                int hi = __double2hiint(s);
                int ee = ((hi >> 20) & 0x7FF) - 1023;
                double mant = __hiloint2double((hi & 0xFFFFF) | 0x3FF00000,
                                               __double2loint(s));
                ll2[b] = (float)ee + flog2((float)mant) + (float)Eacc;
            }
        }
        return;
    }
    // ---- softmax normalizer: one wave per (b,t) row, grid-strided ----
    int wv = (blockIdx.x - BB) * 8 + (threadIdx.x >> 6);
    int lane = threadIdx.x & 63;
    const int stride = LSE_BLOCKS * 8;
    for (int row = wv; row < BB * TT; row += stride) {
        float x = in[(size_t)row * CC + lane];
        float m = x;
        #pragma unroll
        for (int d = 32; d >= 1; d >>= 1) m = fmaxf(m, __shfl_xor(m, d, 64));
        float s = fexp2((x - m) * LOG2E);
        #pragma unroll
        for (int d = 32; d >= 1; d >>= 1) s += __shfl_xor(s, d, 64);
        if (lane == 0) lse[row] = m + flog2(s) * LN2f;
    }
}

// per-batch loss_b = sum_t lse_nat[b,t] - ll2[b]*ln2
__global__ __launch_bounds__(256) void bsum_kernel(const float* __restrict__ lse,
                                                   const float* __restrict__ ll2,
                                                   float* __restrict__ lossb) {
    __shared__ float red[256];
    int b = blockIdx.x;
    float s = 0.f;
    for (int i = threadIdx.x; i < TT; i += 256) s += lse[(size_t)b * TT + i];
    red[threadIdx.x] = s;
    __syncthreads();
    #pragma unroll
    for (int w = 128; w >= 1; w >>= 1) {
        if (threadIdx.x < w) red[threadIdx.x] += red[threadIdx.x + w];
        __syncthreads();
    }
    if (threadIdx.x == 0) lossb[b] = red[0] - ll2[b] * LN2f;
}

// mean over batch
__global__ __launch_bounds__(64) void final_kernel(const float* __restrict__ lossb,
                                                   float* __restrict__ out) {
    int lane = threadIdx.x;
    float v = lossb[lane] + lossb[lane + 64];
    #pragma unroll
    for (int d = 32; d >= 1; d >>= 1) v += __shfl_xor(v, d, 64);
    if (lane == 0) out[0] = v / (float)BB;
}

extern "C" void kernel_launch(void* const* d_in, const int* in_sizes, int n_in,
                              void* d_out, int out_size, void* d_ws, size_t ws_size,
                              hipStream_t stream) {
    const float* in = (const float*)d_in[0];
    const int* tg = (const int*)d_in[1];
    float* out = (float*)d_out;
    float* lse = (float*)d_ws;                 // B*T floats
    float* ll2 = lse + (size_t)BB * TT;        // B floats
    float* lossb = ll2 + BB;                   // B floats

    hipLaunchKernelGGL(fused_kernel, dim3(BB + LSE_BLOCKS), dim3(512), 0, stream,
                       in, tg, lse, ll2);
    hipLaunchKernelGGL(bsum_kernel, dim3(BB), dim3(256), 0, stream, lse, ll2, lossb);
    hipLaunchKernelGGL(final_kernel, dim3(1), dim3(64), 0, stream, lossb, out);
}